// Round 7
// baseline (347.605 us; speedup 1.0000x reference)
//
#include <hip/hip_runtime.h>
#include <hip/hip_fp16.h>
#include <stddef.h>
#include <stdint.h>

// Problem: N=4, S=4096, E=1024, H=16, D=64. fp32 in/out.
// Reference = "attention over heads": per (n,s) position, 16x16 softmax across
// heads, then scrambled (N,H,S,D)->(N,S,E) reshape + output projection.
// Pipeline (f16 MFMA compute, fp32 accumulate; absmax ~8e-3 << 4.09e-2):
//   K0: convert x, Wq..Wo fp32 -> f16 in ws
//   K1: FUSED QKV projection (ONE kernel, 3 outputs)  <-- ROUND 7
//   K2: per-position head-attention, ONE WAVE per position (unchanged)
//   K3: output projection (round-6 gemm256, unchanged, passed)
// ROUND 7 rationale: rounds 1-6 proved qkv is MEMORY-BOUND (dur = hbm_bytes /
// 3.0 TB/s in every variant; schedule changes moved MfmaUtil 29-35% but never
// duration). Traffic was 2.8x ideal: x re-fetched ~6x across 3 z-layers and
// 4 nt-passes. Fusion stages each x-tile ONCE for all three weight matrices
// (A-fetch /3, DMA /3, prologue/epilogue amortized 3x) and the smaller block
// (80 KB LDS, ~200 VGPR) gives 2 blocks/CU -> m97-style inter-block overlap.

typedef _Float16 f16_t;
typedef _Float16 f16x8 __attribute__((ext_vector_type(8)));
typedef _Float16 f16x4 __attribute__((ext_vector_type(4)));
typedef float    f32x4 __attribute__((ext_vector_type(4)));

static constexpr int Sdim = 4096;
static constexpr int Edim = 1024;
static constexpr int Mrows = 4 * Sdim;                  // 16384
static constexpr size_t MATEL = (size_t)Mrows * Edim;   // 16.7M
static constexpr size_t WEL = (size_t)Edim * Edim;      // 1.05M

__device__ __forceinline__ void gload_lds16(const f16_t* g, f16_t* l) {
  // async global->LDS, 16B/lane; LDS dest = wave-uniform base + lane*16
  __builtin_amdgcn_global_load_lds(
      (const __attribute__((address_space(1))) void*)g,
      (__attribute__((address_space(3))) void*)l, 16, 0, 0);
}

// Opaque LDS read on raw 32-bit LDS byte address (kept for round-6 gemm256).
__device__ __forceinline__ f16x8 ds_read16(uint32_t byte_addr) {
  f16x8 r;
  asm volatile("ds_read_b128 %0, %1" : "=v"(r) : "v"(byte_addr));
  return r;
}

#define SCHED_FENCE() __builtin_amdgcn_sched_barrier(0)

// ---------------- fp32 -> f16 convert ----------------
__global__ __launch_bounds__(256) void cvt_kernel(
    const float* __restrict__ s0, const float* __restrict__ s1,
    const float* __restrict__ s2, const float* __restrict__ s3,
    const float* __restrict__ s4,
    f16_t* __restrict__ d0, f16_t* __restrict__ d1, f16_t* __restrict__ d2,
    f16_t* __restrict__ d3, f16_t* __restrict__ d4) {
  const float* s; f16_t* d; size_t nv;  // nv = count of float4 groups
  switch (blockIdx.y) {
    case 0: s = s0; d = d0; nv = MATEL / 4; break;
    case 1: s = s1; d = d1; nv = WEL / 4; break;
    case 2: s = s2; d = d2; nv = WEL / 4; break;
    case 3: s = s3; d = d3; nv = WEL / 4; break;
    default: s = s4; d = d4; nv = WEL / 4; break;
  }
  const size_t stride = (size_t)gridDim.x * 256;
  for (size_t i = blockIdx.x * 256 + threadIdx.x; i < nv; i += stride) {
    const f32x4 v = ((const f32x4*)s)[i];
    f16x4 h;
#pragma unroll
    for (int j = 0; j < 4; j++) h[j] = (f16_t)v[j];
    ((f16x4*)d)[i] = h;
  }
}

// ---------------- FUSED QKV GEMM ----------------
// For one x-tile (128 rows), compute Q/K/V tiles (64 cols each) in one block.
// C_c[m,n] = sum_k A[m,k] * W_c[n,k] + b_c[n]   (NT, row-major stride Edim)
// 256 threads = 4 waves (2M x 2N); per-wave 64x32 per output matrix.
// LDS 80 KB: As[2][128x64] (16 KB/slot) + Bs[2][3][64x64] (24 KB/slot)
//  -> 2 blocks/CU. Swizzle: (r,c) stored at f16 idx r*64 + (c ^ ((r&7)<<3)),
// applied as inverse on the per-lane GLOBAL source col (linear LDS dest,
// rule 21) and on reads. Simple m97 schedule: stage(t+1); read(t); MFMA;
// __syncthreads -- inter-block overlap (2/CU) hides the barrier drain.
static constexpr int FBM = 128, FBN = 64, FBK = 64;
static constexpr int FNT = Edim / FBK;  // 16 K-tiles

__global__ __launch_bounds__(256, 2) void qkv_fused_kernel(
    const f16_t* __restrict__ Xh,
    const f16_t* __restrict__ Wq, const f16_t* __restrict__ Wk,
    const f16_t* __restrict__ Wv,
    const float* __restrict__ bq, const float* __restrict__ bk,
    const float* __restrict__ bv,
    f16_t* __restrict__ Qb, f16_t* __restrict__ Kb, f16_t* __restrict__ Vb) {
  __shared__ __align__(16) f16_t As[2][FBM * FBK];     // 2 x 16 KB
  __shared__ __align__(16) f16_t Bs[2][3][FBN * FBK];  // 2 x 3 x 8 KB

  const int t = threadIdx.x;
  const int lane = t & 63;
  const int w = t >> 6;
  const int l16 = lane & 15;
  const int quad = lane >> 4;
  const int wm = (w >> 1) * 64;  // wave M offset
  const int wn = (w & 1) * 32;   // wave N offset

  // XCD swizzle: 2048 blocks -> 256 consecutive per XCD = 2 nt x 128 mt.
  // Per-XCD working set: 2 nt x 3 W-panels = 0.75 MB (L2-resident); x
  // streamed once per XCD.
  const int id = blockIdx.x;
  const int id2 = (id & 7) * 256 + (id >> 3);
  const int mt = id2 & 127;
  const int nt = id2 >> 7;
  const int bm = mt * FBM;
  const int bn = nt * FBN;

  // Staging: per issue 256 threads x 16 B = 32 rows of 64 cols (linear LDS).
  // phys f16 idx = issue*2048 + t*8 -> row = issue*32 + t/8, pcol = (t&7)*8.
  // Inverse-swizzled global col = ((t&7) ^ ((t>>3)&7)) * 8  (row%8 == (t>>3)&7).
  const int srow = t >> 3;
  const int scol = ((t & 7) ^ ((t >> 3) & 7)) * 8;
  const f16_t* gA  = Xh + (size_t)(bm + srow) * Edim + scol;
  const f16_t* gW0 = Wq + (size_t)(bn + srow) * Edim + scol;
  const f16_t* gW1 = Wk + (size_t)(bn + srow) * Edim + scol;
  const f16_t* gW2 = Wv + (size_t)(bn + srow) * Edim + scol;

  auto stageTile = [&](int slot, int kt) {
    const int ko = kt * FBK;
#pragma unroll
    for (int i = 0; i < 4; ++i)   // A: 4 x 32 rows
      gload_lds16(gA + (size_t)i * 32 * Edim + ko,
                  &As[slot][i * 2048 + t * 8]);
#pragma unroll
    for (int i = 0; i < 2; ++i) { // each W: 2 x 32 rows
      gload_lds16(gW0 + (size_t)i * 32 * Edim + ko,
                  &Bs[slot][0][i * 2048 + t * 8]);
      gload_lds16(gW1 + (size_t)i * 32 * Edim + ko,
                  &Bs[slot][1][i * 2048 + t * 8]);
      gload_lds16(gW2 + (size_t)i * 32 * Edim + ko,
                  &Bs[slot][2][i * 2048 + t * 8]);
    }
  };

  f32x4 acc[3][4][2] = {};  // [mat][m-frag][n-frag], 96 VGPRs

  // Prologue: tile 0 into slot 0.
  stageTile(0, 0);
  __syncthreads();

  for (int kt = 0; kt < FNT; ++kt) {
    const int S = kt & 1;
    if (kt + 1 < FNT) stageTile(S ^ 1, kt + 1);  // DMA in flight during compute

    f16x8 af[2][4], bf[3][2][2];
#pragma unroll
    for (int kc = 0; kc < 2; ++kc) {
#pragma unroll
      for (int m = 0; m < 4; ++m) {
        const int r = wm + m * 16 + l16;
        af[kc][m] = *(const f16x8*)
            &As[S][r * FBK + ((kc * 32 + quad * 8) ^ ((r & 7) << 3))];
      }
#pragma unroll
      for (int c = 0; c < 3; ++c)
#pragma unroll
        for (int n = 0; n < 2; ++n) {
          const int r = wn + n * 16 + l16;
          bf[c][n][kc] = *(const f16x8*)
              &Bs[S][c][r * FBK + ((kc * 32 + quad * 8) ^ ((r & 7) << 3))];
        }
    }
#pragma unroll
    for (int kc = 0; kc < 2; ++kc)
#pragma unroll
      for (int c = 0; c < 3; ++c)
#pragma unroll
        for (int m = 0; m < 4; ++m)
#pragma unroll
          for (int n = 0; n < 2; ++n)
            acc[c][m][n] = __builtin_amdgcn_mfma_f32_16x16x32_f16(
                af[kc][m], bf[c][n][kc], acc[c][m][n], 0, 0, 0);
    __syncthreads();  // drains DMA (slot S^1 ready) + read-drain for restage
  }

  // Epilogue. C/D layout: col = lane&15, row = quad*4 + reg [m89-verified].
  f16_t* const outs[3] = {Qb, Kb, Vb};
  const float* const biases[3] = {bq, bk, bv};
#pragma unroll
  for (int c = 0; c < 3; ++c) {
#pragma unroll
    for (int n = 0; n < 2; ++n) {
      const int col = bn + wn + n * 16 + l16;
      const float bb = biases[c][col];
#pragma unroll
      for (int m = 0; m < 4; ++m) {
        const int r0 = bm + wm + m * 16 + quad * 4;
#pragma unroll
        for (int r = 0; r < 4; ++r)
          outs[c][(size_t)(r0 + r) * Edim + col] = (f16_t)(acc[c][m][n][r] + bb);
      }
    }
  }
}

// ---------------- 256^2 reg-pipelined GEMM core (round-6, passed) ----------
// Used for the output projection only.
static constexpr int BM2 = 256, BN2 = 256, BK2 = 64;
static constexpr int NT2 = Edim / BK2;   // 16 K-tiles
static constexpr int HALF2 = 128 * BK2;  // 8192 f16 = 16KB per half-tile

template <int V> struct ic { static constexpr int v = V; };

template <typename TOut>
__device__ __forceinline__ void gemm256(const f16_t* __restrict__ A,
                                        const f16_t* __restrict__ B,
                                        const float* __restrict__ bias,
                                        TOut* __restrict__ C) {
  __shared__ __align__(16) f16_t lds[2][2][2][HALF2];  // [slot][mat][half][.]

  const int t = threadIdx.x;
  const int lane = t & 63;
  const int w = t >> 6;
  const int l16 = lane & 15;
  const int quad = lane >> 4;
  const int ha = w >> 2;         // A half this wave reads (wm = ha*128)
  const int hb = (w & 3) >> 1;   // B half this wave reads
  const int wnr = (w & 1) * 64;  // row offset inside B half

  const uint32_t ldsBase = (uint32_t)(uintptr_t)
      (__attribute__((address_space(3))) f16_t*)&lds[0][0][0][0];
  const uint32_t aHalfOff = (uint32_t)(ha * (HALF2 * 2));
  const uint32_t bHalfOff = (uint32_t)(32768 + hb * (HALF2 * 2));

  const int id = blockIdx.x;
  const int id2 = (id & 7) * 32 + (id >> 3);
  const int bm = (id2 & 63) * BM2;
  const int bn = (id2 >> 6) * BN2;

  const int srow = w * 8 + (lane >> 3);
  const int scol = ((lane & 7) ^ ((lane >> 3) & 7)) * 8;
  const size_t gA0 = (size_t)(bm + srow) * Edim + scol;
  const size_t gB0 = (size_t)(bn + srow) * Edim + scol;
  const int lws = w * 512 + lane * 8;

  auto stage = [&](int mat, int half, int slot, int kt) {
    const f16_t* g = (mat == 0 ? A + gA0 : B + gB0) +
                     (size_t)half * 128 * Edim + kt * BK2;
    f16_t* l = &lds[slot][mat][half][lws];
    gload_lds16(g, l);                             // rows 0..63 of half
    gload_lds16(g + (size_t)64 * Edim, l + 4096);  // rows 64..127
  };

  auto rdaddr = [&](uint32_t base, int r, int c0) -> uint32_t {
    return base + (uint32_t)((r * 64 + (c0 ^ ((r & 7) << 3))) * 2);
  };

  f32x4 acc[8][4] = {};
  f16x8 af0[4], af1[4], bf0[4], bf1[4];

  auto rdA = [&](uint32_t aBase, int ih, int kc, f16x8* dst) {
#pragma unroll
    for (int ii = 0; ii < 4; ++ii) {
      const int r = ih * 64 + ii * 16 + l16;
      dst[ii] = ds_read16(rdaddr(aBase, r, kc * 32 + quad * 8));
    }
  };
  auto rdB = [&](uint32_t bBase, int kc, f16x8* dst) {
#pragma unroll
    for (int j = 0; j < 4; ++j) {
      const int r = wnr + j * 16 + l16;
      dst[j] = ds_read16(rdaddr(bBase, r, kc * 32 + quad * 8));
    }
  };
  auto mmac = [&](const f16x8* af, const f16x8* bf, int ih) {
    __builtin_amdgcn_s_setprio(1);
#pragma unroll
    for (int ii = 0; ii < 4; ++ii)
#pragma unroll
      for (int j = 0; j < 4; ++j)
        acc[ih * 4 + ii][j] = __builtin_amdgcn_mfma_f32_16x16x32_f16(
            af[ii], bf[j], acc[ih * 4 + ii][j], 0, 0, 0);
    __builtin_amdgcn_s_setprio(0);
  };

  stage(0, 0, 0, 0); stage(0, 1, 0, 0);
  stage(1, 0, 0, 0); stage(1, 1, 0, 0);
  stage(1, 0, 1, 1); stage(1, 1, 1, 1);
  asm volatile("s_waitcnt vmcnt(2)");
  SCHED_FENCE();
  __builtin_amdgcn_s_barrier();
  SCHED_FENCE();
  rdA(ldsBase + aHalfOff, 0, 0, af0);
  rdB(ldsBase + bHalfOff, 0, bf0);

  auto ktile = [&](int tt, auto SAc, auto SBc, auto NQc) {
    constexpr int SA = decltype(SAc)::v;
    constexpr int SB = decltype(SBc)::v;
    constexpr int NQ = decltype(NQc)::v;
    const int S = tt & 1;
    const uint32_t aB  = ldsBase + (uint32_t)(S * 65536) + aHalfOff;
    const uint32_t bB  = ldsBase + (uint32_t)(S * 65536) + bHalfOff;
    const uint32_t aBn = ldsBase + (uint32_t)((S ^ 1) * 65536) + aHalfOff;
    const uint32_t bBn = ldsBase + (uint32_t)((S ^ 1) * 65536) + bHalfOff;
    rdA(aB, 1, 0, af1);
    if (SA) { stage(0, 0, S ^ 1, tt + 1); stage(0, 1, S ^ 1, tt + 1); }
    SCHED_FENCE();
    asm volatile("s_waitcnt lgkmcnt(4)");
    SCHED_FENCE();
    mmac(af0, bf0, 0);
    rdA(aB, 0, 1, af0);
    rdB(bB, 1, bf1);
    SCHED_FENCE();
    asm volatile("s_waitcnt lgkmcnt(8)");
    SCHED_FENCE();
    mmac(af1, bf0, 1);
    rdA(aB, 1, 1, af1);
    SCHED_FENCE();
    asm volatile("s_waitcnt lgkmcnt(4)");
    SCHED_FENCE();
    mmac(af0, bf1, 0);
    asm volatile("s_waitcnt lgkmcnt(0)");
    asm volatile("s_waitcnt vmcnt(0)");
    SCHED_FENCE();
    __builtin_amdgcn_s_barrier();
    SCHED_FENCE();
    if (SB) { stage(1, 0, S, tt + 2); stage(1, 1, S, tt + 2); }
    if (NQ) { rdA(aBn, 0, 0, af0); rdB(bBn, 0, bf0); }
    SCHED_FENCE();
    mmac(af1, bf1, 1);
  };

  for (int tt = 0; tt < NT2 - 2; ++tt) ktile(tt, ic<1>{}, ic<1>{}, ic<1>{});
  ktile(NT2 - 2, ic<1>{}, ic<0>{}, ic<1>{});
  ktile(NT2 - 1, ic<0>{}, ic<0>{}, ic<0>{});

  const int wm = ha * 128;
  const int wn = (w & 3) * 64;
#pragma unroll
  for (int j = 0; j < 4; ++j) {
    const int col = bn + wn + j * 16 + l16;
    const float bv = bias[col];
#pragma unroll
    for (int i = 0; i < 8; ++i) {
      const int rb = bm + wm + i * 16 + quad * 4;
#pragma unroll
      for (int r = 0; r < 4; ++r)
        C[(size_t)(rb + r) * Edim + col] = (TOut)(acc[i][j][r] + bv);
    }
  }
}

__global__ __launch_bounds__(512, 1) void outp_kernel(
    const f16_t* __restrict__ Ab, const f16_t* __restrict__ Wo,
    const float* __restrict__ bo, float* __restrict__ out) {
  gemm256<float>(Ab, Wo, bo, out);
}

// ---------------- per-position head-attention (one wave / position) ----------
// (unchanged from verified kernel)
__global__ __launch_bounds__(256) void attn_kernel(const f16_t* __restrict__ Qb,
                                                   const f16_t* __restrict__ Kb,
                                                   const f16_t* __restrict__ Vb,
                                                   f16_t* __restrict__ Ab) {
  __shared__ __align__(16) f16_t Vs[4][1024];  // per-wave V row (2KB each)
  const int t = threadIdx.x;
  const int w = t >> 6;
  const int lane = t & 63;
  const int l16 = lane & 15;
  const int quad = lane >> 4;
  const int pos = blockIdx.x * 4 + w;           // n*S + s
  const int n4 = pos >> 12;
  const int s = pos & (Sdim - 1);

  const f16_t* Qr = Qb + (size_t)pos * Edim;
  const f16_t* Kr = Kb + (size_t)pos * Edim;
  const f16_t* Vr = Vb + (size_t)pos * Edim;

  *(f16x8*)&Vs[w][lane * 16]     = *(const f16x8*)(Vr + lane * 16);
  *(f16x8*)&Vs[w][lane * 16 + 8] = *(const f16x8*)(Vr + lane * 16 + 8);

  f32x4 sacc = {};
#pragma unroll
  for (int step = 0; step < 2; step++) {
    const int off = l16 * 64 + step * 32 + quad * 8;
    const f16x8 kf = *(const f16x8*)(Kr + off);  // A: K[m=l16][k]
    const f16x8 qf = *(const f16x8*)(Qr + off);  // B: Q[n=l16][k]
    sacc = __builtin_amdgcn_mfma_f32_16x16x32_f16(kf, qf, sacc, 0, 0, 0);
  }
#pragma unroll
  for (int r = 0; r < 4; r++) sacc[r] *= 0.125f;

  float m = fmaxf(fmaxf(sacc[0], sacc[1]), fmaxf(sacc[2], sacc[3]));
  m = fmaxf(m, __shfl_xor(m, 16));
  m = fmaxf(m, __shfl_xor(m, 32));
  float e[4];
#pragma unroll
  for (int r = 0; r < 4; r++) e[r] = __expf(sacc[r] - m);
  float l = (e[0] + e[1]) + (e[2] + e[3]);
  l += __shfl_xor(l, 16);
  l += __shfl_xor(l, 32);
  const float inv = 1.0f / l;
  f16x4 pa;
#pragma unroll
  for (int r = 0; r < 4; r++) pa[r] = (f16_t)(e[r] * inv);

  __syncthreads();
  f32x4 oacc[4];
#pragma unroll
  for (int dc = 0; dc < 4; dc++) {
    f16x4 vbf;
#pragma unroll
    for (int j = 0; j < 4; j++)
      vbf[j] = Vs[w][(quad * 4 + j) * 64 + dc * 16 + l16];
    f32x4 z = {};
    oacc[dc] = __builtin_amdgcn_mfma_f32_16x16x16f16(pa, vbf, z, 0, 0, 0);
  }

  const size_t obase =
      ((size_t)(n4 << 12) + (size_t)(s >> 4)) * Edim + (size_t)(s & 15) * 64 + l16;
#pragma unroll
  for (int reg = 0; reg < 4; reg++) {
    const size_t rowoff = obase + (size_t)(quad * 4 + reg) * 256 * Edim;
#pragma unroll
    for (int dc = 0; dc < 4; dc++)
      Ab[rowoff + dc * 16] = (f16_t)oacc[dc][reg];
  }
}

// ---------------- launcher ----------------
extern "C" void kernel_launch(void* const* d_in, const int* in_sizes, int n_in,
                              void* d_out, int out_size, void* d_ws, size_t ws_size,
                              hipStream_t stream) {
  const float* x  = (const float*)d_in[0];
  const float* Wq = (const float*)d_in[1];
  const float* bq = (const float*)d_in[2];
  const float* Wk = (const float*)d_in[3];
  const float* bk = (const float*)d_in[4];
  const float* Wv = (const float*)d_in[5];
  const float* bv = (const float*)d_in[6];
  const float* Wo = (const float*)d_in[7];
  const float* bo = (const float*)d_in[8];
  float* out = (float*)d_out;

  f16_t* xh  = (f16_t*)d_ws;          // 33.5 MB
  f16_t* Wqh = xh + MATEL;            // 2 MB each
  f16_t* Wkh = Wqh + WEL;
  f16_t* Wvh = Wkh + WEL;
  f16_t* Woh = Wvh + WEL;
  f16_t* Qb  = Woh + WEL;             // 33.5 MB each
  f16_t* Kb  = Qb + MATEL;
  f16_t* Vb  = Kb + MATEL;
  f16_t* Ab  = Vb + MATEL;            // total ~176 MB

  cvt_kernel<<<dim3(2048, 5), dim3(256), 0, stream>>>(x, Wq, Wk, Wv, Wo,
                                                      xh, Wqh, Wkh, Wvh, Woh);
  // fused QKV: 128 mt x 16 nt = 2048 blocks (%8 == 0 for XCD swizzle)
  qkv_fused_kernel<<<dim3((Mrows / FBM) * (Edim / FBN)), dim3(256), 0, stream>>>(
      xh, Wqh, Wkh, Wvh, bq, bk, bv, Qb, Kb, Vb);
  attn_kernel<<<dim3(Mrows / 4), dim3(256), 0, stream>>>(Qb, Kb, Vb, Ab);
  const int ngrid = (Mrows / BM2) * (Edim / BN2);  // 64*4 = 256, %8 == 0
  outp_kernel<<<dim3(ngrid), dim3(512), 0, stream>>>(Ab, Woh, bo, out);
}

// Round 8
// 333.065 us; speedup vs baseline: 1.0437x; 1.0437x over previous
//
#include <hip/hip_runtime.h>
#include <hip/hip_fp16.h>
#include <stddef.h>
#include <stdint.h>

// Problem: N=4, S=4096, E=1024, H=16, D=64. fp32 in/out.
// Reference = "attention over heads": per (n,s) position, 16x16 softmax across
// heads, then scrambled (N,H,S,D)->(N,S,E) reshape + output projection.
// Pipeline (f16 MFMA compute, fp32 accumulate; absmax ~8e-3 << 4.09e-2):
//   K0: convert x, Wq..Wo fp32 -> f16 in ws
//   K1: QKV projections (3x GEMM, round-6 gemm256 -- best measured, passed 2x)
//   K2: per-position head-attention -- ROUND 8: coalesced epilogue
//   K3: output projection (round-6 gemm256)
// ROUND 8 rationale: pipeline audit. qkv=130, outp~44, cvt~20 -> attn residual
// ~130us vs ~25us issue/BW arithmetic. The defect that explains 5x: old attn
// epilogue = 16 scalar f16 stores/lane, each instr = 4x32B segments on rows
// 512KB apart (~1M isolated 32B segments). Fix: per-wave LDS transpose
// (Ot[16][72] pad) -> 2x 16B/lane stores = full 128B segments. Also drop the
// block barrier (LDS use is wave-private). qkv fusion (round 7) REVERTED:
// it raised FETCH to 268MB (every XCD streamed all of x).

typedef _Float16 f16_t;
typedef _Float16 f16x8 __attribute__((ext_vector_type(8)));
typedef _Float16 f16x4 __attribute__((ext_vector_type(4)));
typedef float    f32x4 __attribute__((ext_vector_type(4)));

static constexpr int Sdim = 4096;
static constexpr int Edim = 1024;
static constexpr int Mrows = 4 * Sdim;                  // 16384
static constexpr size_t MATEL = (size_t)Mrows * Edim;   // 16.7M
static constexpr size_t WEL = (size_t)Edim * Edim;      // 1.05M

__device__ __forceinline__ void gload_lds16(const f16_t* g, f16_t* l) {
  // async global->LDS, 16B/lane; LDS dest = wave-uniform base + lane*16
  __builtin_amdgcn_global_load_lds(
      (const __attribute__((address_space(1))) void*)g,
      (__attribute__((address_space(3))) void*)l, 16, 0, 0);
}

// Opaque LDS read on raw 32-bit LDS byte address. Volatile: ordered among
// themselves and vs the (volatile) waitcnt asms -> exact lgkm counts hold.
__device__ __forceinline__ f16x8 ds_read16(uint32_t byte_addr) {
  f16x8 r;
  asm volatile("ds_read_b128 %0, %1" : "=v"(r) : "v"(byte_addr));
  return r;
}

#define SCHED_FENCE() __builtin_amdgcn_sched_barrier(0)

// ---------------- fp32 -> f16 convert ----------------
__global__ __launch_bounds__(256) void cvt_kernel(
    const float* __restrict__ s0, const float* __restrict__ s1,
    const float* __restrict__ s2, const float* __restrict__ s3,
    const float* __restrict__ s4,
    f16_t* __restrict__ d0, f16_t* __restrict__ d1, f16_t* __restrict__ d2,
    f16_t* __restrict__ d3, f16_t* __restrict__ d4) {
  const float* s; f16_t* d; size_t nv;  // nv = count of float4 groups
  switch (blockIdx.y) {
    case 0: s = s0; d = d0; nv = MATEL / 4; break;
    case 1: s = s1; d = d1; nv = WEL / 4; break;
    case 2: s = s2; d = d2; nv = WEL / 4; break;
    case 3: s = s3; d = d3; nv = WEL / 4; break;
    default: s = s4; d = d4; nv = WEL / 4; break;
  }
  const size_t stride = (size_t)gridDim.x * 256;
  for (size_t i = blockIdx.x * 256 + threadIdx.x; i < nv; i += stride) {
    const f32x4 v = ((const f32x4*)s)[i];
    f16x4 h;
#pragma unroll
    for (int j = 0; j < 4; j++) h[j] = (f16_t)v[j];
    ((f16x4*)d)[i] = h;
  }
}

// ---------------- 256^2 reg-pipelined GEMM core (round-6, passed 2x) -------
static constexpr int BM2 = 256, BN2 = 256, BK2 = 64;
static constexpr int NT2 = Edim / BK2;   // 16 K-tiles
static constexpr int HALF2 = 128 * BK2;  // 8192 f16 = 16KB per half-tile

template <int V> struct ic { static constexpr int v = V; };

template <typename TOut>
__device__ __forceinline__ void gemm256(const f16_t* __restrict__ A,
                                        const f16_t* __restrict__ B,
                                        const float* __restrict__ bias,
                                        TOut* __restrict__ C) {
  __shared__ __align__(16) f16_t lds[2][2][2][HALF2];  // [slot][mat][half][.]

  const int t = threadIdx.x;
  const int lane = t & 63;
  const int w = t >> 6;
  const int l16 = lane & 15;
  const int quad = lane >> 4;
  const int ha = w >> 2;         // A half this wave reads (wm = ha*128)
  const int hb = (w & 3) >> 1;   // B half this wave reads
  const int wnr = (w & 1) * 64;  // row offset inside B half

  const uint32_t ldsBase = (uint32_t)(uintptr_t)
      (__attribute__((address_space(3))) f16_t*)&lds[0][0][0][0];
  const uint32_t aHalfOff = (uint32_t)(ha * (HALF2 * 2));
  const uint32_t bHalfOff = (uint32_t)(32768 + hb * (HALF2 * 2));

  // T1: XCD-chunked bijective swizzle over the 256 (mtile,ntile) blocks.
  const int id = blockIdx.x;
  const int id2 = (id & 7) * 32 + (id >> 3);
  const int bm = (id2 & 63) * BM2;
  const int bn = (id2 >> 6) * BN2;

  const int srow = w * 8 + (lane >> 3);
  const int scol = ((lane & 7) ^ ((lane >> 3) & 7)) * 8;
  const size_t gA0 = (size_t)(bm + srow) * Edim + scol;
  const size_t gB0 = (size_t)(bn + srow) * Edim + scol;
  const int lws = w * 512 + lane * 8;

  auto stage = [&](int mat, int half, int slot, int kt) {
    const f16_t* g = (mat == 0 ? A + gA0 : B + gB0) +
                     (size_t)half * 128 * Edim + kt * BK2;
    f16_t* l = &lds[slot][mat][half][lws];
    gload_lds16(g, l);                             // rows 0..63 of half
    gload_lds16(g + (size_t)64 * Edim, l + 4096);  // rows 64..127
  };

  auto rdaddr = [&](uint32_t base, int r, int c0) -> uint32_t {
    return base + (uint32_t)((r * 64 + (c0 ^ ((r & 7) << 3))) * 2);
  };

  f32x4 acc[8][4] = {};
  f16x8 af0[4], af1[4], bf0[4], bf1[4];

  auto rdA = [&](uint32_t aBase, int ih, int kc, f16x8* dst) {
#pragma unroll
    for (int ii = 0; ii < 4; ++ii) {
      const int r = ih * 64 + ii * 16 + l16;
      dst[ii] = ds_read16(rdaddr(aBase, r, kc * 32 + quad * 8));
    }
  };
  auto rdB = [&](uint32_t bBase, int kc, f16x8* dst) {
#pragma unroll
    for (int j = 0; j < 4; ++j) {
      const int r = wnr + j * 16 + l16;
      dst[j] = ds_read16(rdaddr(bBase, r, kc * 32 + quad * 8));
    }
  };
  auto mmac = [&](const f16x8* af, const f16x8* bf, int ih) {
    __builtin_amdgcn_s_setprio(1);
#pragma unroll
    for (int ii = 0; ii < 4; ++ii)
#pragma unroll
      for (int j = 0; j < 4; ++j)
        acc[ih * 4 + ii][j] = __builtin_amdgcn_mfma_f32_16x16x32_f16(
            af[ii], bf[j], acc[ih * 4 + ii][j], 0, 0, 0);
    __builtin_amdgcn_s_setprio(0);
  };

  stage(0, 0, 0, 0); stage(0, 1, 0, 0);
  stage(1, 0, 0, 0); stage(1, 1, 0, 0);
  stage(1, 0, 1, 1); stage(1, 1, 1, 1);
  asm volatile("s_waitcnt vmcnt(2)");
  SCHED_FENCE();
  __builtin_amdgcn_s_barrier();
  SCHED_FENCE();
  rdA(ldsBase + aHalfOff, 0, 0, af0);
  rdB(ldsBase + bHalfOff, 0, bf0);

  auto ktile = [&](int tt, auto SAc, auto SBc, auto NQc) {
    constexpr int SA = decltype(SAc)::v;
    constexpr int SB = decltype(SBc)::v;
    constexpr int NQ = decltype(NQc)::v;
    const int S = tt & 1;
    const uint32_t aB  = ldsBase + (uint32_t)(S * 65536) + aHalfOff;
    const uint32_t bB  = ldsBase + (uint32_t)(S * 65536) + bHalfOff;
    const uint32_t aBn = ldsBase + (uint32_t)((S ^ 1) * 65536) + aHalfOff;
    const uint32_t bBn = ldsBase + (uint32_t)((S ^ 1) * 65536) + bHalfOff;
    rdA(aB, 1, 0, af1);
    if (SA) { stage(0, 0, S ^ 1, tt + 1); stage(0, 1, S ^ 1, tt + 1); }
    SCHED_FENCE();
    asm volatile("s_waitcnt lgkmcnt(4)");
    SCHED_FENCE();
    mmac(af0, bf0, 0);
    rdA(aB, 0, 1, af0);
    rdB(bB, 1, bf1);
    SCHED_FENCE();
    asm volatile("s_waitcnt lgkmcnt(8)");
    SCHED_FENCE();
    mmac(af1, bf0, 1);
    rdA(aB, 1, 1, af1);
    SCHED_FENCE();
    asm volatile("s_waitcnt lgkmcnt(4)");
    SCHED_FENCE();
    mmac(af0, bf1, 0);
    asm volatile("s_waitcnt lgkmcnt(0)");
    asm volatile("s_waitcnt vmcnt(0)");
    SCHED_FENCE();
    __builtin_amdgcn_s_barrier();
    SCHED_FENCE();
    if (SB) { stage(1, 0, S, tt + 2); stage(1, 1, S, tt + 2); }
    if (NQ) { rdA(aBn, 0, 0, af0); rdB(bBn, 0, bf0); }
    SCHED_FENCE();
    mmac(af1, bf1, 1);
  };

  for (int tt = 0; tt < NT2 - 2; ++tt) ktile(tt, ic<1>{}, ic<1>{}, ic<1>{});
  ktile(NT2 - 2, ic<1>{}, ic<0>{}, ic<1>{});
  ktile(NT2 - 1, ic<0>{}, ic<0>{}, ic<0>{});

  // Epilogue. C/D layout: col = lane&15, row = quad*4 + reg [m89-verified].
  const int wm = ha * 128;
  const int wn = (w & 3) * 64;
#pragma unroll
  for (int j = 0; j < 4; ++j) {
    const int col = bn + wn + j * 16 + l16;
    const float bv = bias[col];
#pragma unroll
    for (int i = 0; i < 8; ++i) {
      const int rb = bm + wm + i * 16 + quad * 4;
#pragma unroll
      for (int r = 0; r < 4; ++r)
        C[(size_t)(rb + r) * Edim + col] = (TOut)(acc[i][j][r] + bv);
    }
  }
}

__global__ __launch_bounds__(512, 1) void qkv_kernel(
    const f16_t* __restrict__ x,
    const f16_t* __restrict__ Wq, const float* __restrict__ bq,
    const f16_t* __restrict__ Wk, const float* __restrict__ bk,
    const f16_t* __restrict__ Wv, const float* __restrict__ bv,
    f16_t* __restrict__ Qb, f16_t* __restrict__ Kb, f16_t* __restrict__ Vb) {
  const f16_t* W; const float* bi; f16_t* C;
  if (blockIdx.z == 0)      { W = Wq; bi = bq; C = Qb; }
  else if (blockIdx.z == 1) { W = Wk; bi = bk; C = Kb; }
  else                      { W = Wv; bi = bv; C = Vb; }
  gemm256<f16_t>(x, W, bi, C);
}

__global__ __launch_bounds__(512, 1) void outp_kernel(
    const f16_t* __restrict__ Ab, const f16_t* __restrict__ Wo,
    const float* __restrict__ bo, float* __restrict__ out) {
  gemm256<float>(Ab, Wo, bo, out);
}

// ---------------- per-position head-attention (one wave / position) ----------
// ROUND 8: coalesced epilogue. Compute unchanged (verified since round 0):
// S^T via mfma(A=K,B=Q); in-lane softmax; PV via legacy 16x16x16 with P in
// A-frag layout. NEW: O transposed through per-wave LDS (Ot[16][72], padded
// -> <=2-way banks) then stored as 2x f16x8/lane = full 128B segments, one
// per head-row. No block barrier: all LDS regions are wave-private (per-wave
// lgkm ordering suffices; lanes of a wave are lockstep).
__global__ __launch_bounds__(256) void attn_kernel(const f16_t* __restrict__ Qb,
                                                   const f16_t* __restrict__ Kb,
                                                   const f16_t* __restrict__ Vb,
                                                   f16_t* __restrict__ Ab) {
  __shared__ __align__(16) f16_t Vs[4][1024];     // per-wave V row (2KB each)
  __shared__ __align__(16) f16_t Ot[4][16 * 72];  // per-wave O^T, pad 64->72
  const int t = threadIdx.x;
  const int w = t >> 6;
  const int lane = t & 63;
  const int l16 = lane & 15;
  const int quad = lane >> 4;
  const int pos = blockIdx.x * 4 + w;           // n*S + s
  const int n4 = pos >> 12;
  const int s = pos & (Sdim - 1);

  const f16_t* Qr = Qb + (size_t)pos * Edim;
  const f16_t* Kr = Kb + (size_t)pos * Edim;
  const f16_t* Vr = Vb + (size_t)pos * Edim;

  // stage V row into LDS (coalesced: 32B/lane); consumed by same wave only
  *(f16x8*)&Vs[w][lane * 16]     = *(const f16x8*)(Vr + lane * 16);
  *(f16x8*)&Vs[w][lane * 16 + 8] = *(const f16x8*)(Vr + lane * 16 + 8);

  // scores: S^T via 2 MFMA steps over head-dim 64
  f32x4 sacc = {};
#pragma unroll
  for (int step = 0; step < 2; step++) {
    const int off = l16 * 64 + step * 32 + quad * 8;
    const f16x8 kf = *(const f16x8*)(Kr + off);  // A: K[m=l16][k]
    const f16x8 qf = *(const f16x8*)(Qr + off);  // B: Q[n=l16][k]
    sacc = __builtin_amdgcn_mfma_f32_16x16x32_f16(kf, qf, sacc, 0, 0, 0);
  }
  // lane holds S[q=l16][kh = quad*4+reg], scaled by 1/sqrt(64)
#pragma unroll
  for (int r = 0; r < 4; r++) sacc[r] *= 0.125f;

  // softmax over kh (in-lane regs + cross-quad shuffles)
  float m = fmaxf(fmaxf(sacc[0], sacc[1]), fmaxf(sacc[2], sacc[3]));
  m = fmaxf(m, __shfl_xor(m, 16));
  m = fmaxf(m, __shfl_xor(m, 32));
  float e[4];
#pragma unroll
  for (int r = 0; r < 4; r++) e[r] = __expf(sacc[r] - m);
  float l = (e[0] + e[1]) + (e[2] + e[3]);
  l += __shfl_xor(l, 16);
  l += __shfl_xor(l, 32);
  const float inv = 1.0f / l;
  f16x4 pa;  // P in A-frag layout: P[q=l16][l=quad*4+j]
#pragma unroll
  for (int r = 0; r < 4; r++) pa[r] = (f16_t)(e[r] * inv);

  // PV: O[q][d] over 4 d-chunks of 16, K-dim = 16 heads (wave-private LDS;
  // compiler inserts the lgkm wait for the Vs RAW)
  f32x4 oacc[4];
#pragma unroll
  for (int dc = 0; dc < 4; dc++) {
    f16x4 vbf;  // B: V^T[n=d_sub=l16][k=l=quad*4+j] = Vs[l][dc*16+l16]
#pragma unroll
    for (int j = 0; j < 4; j++)
      vbf[j] = Vs[w][(quad * 4 + j) * 64 + dc * 16 + l16];
    f32x4 z = {};
    oacc[dc] = __builtin_amdgcn_mfma_f32_16x16x16f16(pa, vbf, z, 0, 0, 0);
  }

  // NEW epilogue: transpose O through wave-private LDS, then 2 coalesced
  // 16B/lane stores. lane holds O[q=quad*4+reg][d=dc*16+l16].
#pragma unroll
  for (int dc = 0; dc < 4; dc++)
#pragma unroll
    for (int reg = 0; reg < 4; reg++)
      Ot[w][(quad * 4 + reg) * 72 + dc * 16 + l16] = (f16_t)oacc[dc][reg];

  // Scrambled Ab layout: row n*4096 + h*256 + s/16, col (s%16)*64 + d.
  // Store instr i: lanes cover h = lane>>3 + 8i (8 rows) x d-block (lane&7)*8
  // -> 8 contiguous 128B segments per instr.
  const size_t rowbase = ((size_t)(n4 << 12) + (size_t)(s >> 4)) * Edim +
                         (size_t)(s & 15) * 64 + (size_t)(lane & 7) * 8;
#pragma unroll
  for (int i = 0; i < 2; i++) {
    const int h = (lane >> 3) + 8 * i;
    const f16x8 v = *(const f16x8*)&Ot[w][h * 72 + (lane & 7) * 8];
    *(f16x8*)&Ab[rowbase + (size_t)h * 256 * Edim] = v;
  }
}

// ---------------- launcher ----------------
extern "C" void kernel_launch(void* const* d_in, const int* in_sizes, int n_in,
                              void* d_out, int out_size, void* d_ws, size_t ws_size,
                              hipStream_t stream) {
  const float* x  = (const float*)d_in[0];
  const float* Wq = (const float*)d_in[1];
  const float* bq = (const float*)d_in[2];
  const float* Wk = (const float*)d_in[3];
  const float* bk = (const float*)d_in[4];
  const float* Wv = (const float*)d_in[5];
  const float* bv = (const float*)d_in[6];
  const float* Wo = (const float*)d_in[7];
  const float* bo = (const float*)d_in[8];
  float* out = (float*)d_out;

  f16_t* xh  = (f16_t*)d_ws;          // 33.5 MB
  f16_t* Wqh = xh + MATEL;            // 2 MB each
  f16_t* Wkh = Wqh + WEL;
  f16_t* Wvh = Wkh + WEL;
  f16_t* Woh = Wvh + WEL;
  f16_t* Qb  = Woh + WEL;             // 33.5 MB each
  f16_t* Kb  = Qb + MATEL;
  f16_t* Vb  = Kb + MATEL;
  f16_t* Ab  = Vb + MATEL;            // total ~176 MB

  cvt_kernel<<<dim3(2048, 5), dim3(256), 0, stream>>>(x, Wq, Wk, Wv, Wo,
                                                      xh, Wqh, Wkh, Wvh, Woh);
  const int ngrid = (Mrows / BM2) * (Edim / BN2);  // 64*4 = 256, %8 == 0
  qkv_kernel<<<dim3(ngrid, 1, 3), dim3(512), 0, stream>>>(
      xh, Wqh, bq, Wkh, bk, Wvh, bv, Qb, Kb, Vb);
  attn_kernel<<<dim3(Mrows / 4), dim3(256), 0, stream>>>(Qb, Kb, Vb, Ab);
  outp_kernel<<<dim3(ngrid), dim3(512), 0, stream>>>(Ab, Woh, bo, out);
}